// Round 3
// baseline (393.652 us; speedup 1.0000x reference)
//
#include <hip/hip_runtime.h>
#include <hip/hip_bf16.h>

typedef unsigned short u16;
typedef __attribute__((ext_vector_type(8))) short bf16x8;
typedef __attribute__((ext_vector_type(4))) float f32x4;

#define MFMA_BF16(a,b,c) __builtin_amdgcn_mfma_f32_16x16x32_bf16((a),(b),(c),0,0,0)

__device__ __forceinline__ u16 f2b(float f) {
    __hip_bfloat16 h = __float2bfloat16(f);
    u16 u; __builtin_memcpy(&u, &h, 2); return u;
}
__device__ __forceinline__ f32x4 zero4() { f32x4 z = {0.f,0.f,0.f,0.f}; return z; }

// ---------------- convert x (f32) -> bf16, 8 elems/thread ----------------
__global__ __launch_bounds__(256) void convX(const float* __restrict__ in, u16* __restrict__ out) {
    size_t i = ((size_t)blockIdx.x * 256 + threadIdx.x) * 8;
    float4 a = *(const float4*)(in + i);
    float4 b = *(const float4*)(in + i + 4);
    union { u16 s[8]; uint4 v; } u;
    u.s[0]=f2b(a.x); u.s[1]=f2b(a.y); u.s[2]=f2b(a.z); u.s[3]=f2b(a.w);
    u.s[4]=f2b(b.x); u.s[5]=f2b(b.y); u.s[6]=f2b(b.z); u.s[7]=f2b(b.w);
    *(uint4*)(out + i) = u.v;
}

// ------ weight transpose+convert: in [768][C] f32 -> out [C][768] bf16 ------
__global__ __launch_bounds__(256) void convTW(const float* __restrict__ in, u16* __restrict__ out, int C) {
    __shared__ __align__(16) u16 T[64][68];
    int c0 = blockIdx.x * 64, k0 = blockIdx.y * 64;
    int tid = threadIdx.x;
#pragma unroll
    for (int i = 0; i < 4; ++i) {
        int id = tid + i * 256;
        int row = id >> 4, ch = id & 15;
        float4 v = *(const float4*)(in + (size_t)(k0 + row) * C + c0 + ch * 4);
        T[row][ch*4+0] = f2b(v.x); T[row][ch*4+1] = f2b(v.y);
        T[row][ch*4+2] = f2b(v.z); T[row][ch*4+3] = f2b(v.w);
    }
    __syncthreads();
#pragma unroll
    for (int i = 0; i < 2; ++i) {
        int id = tid + i * 256;
        int c = id >> 3, ch = id & 7;
        union { u16 s[8]; uint4 v; } u;
#pragma unroll
        for (int j = 0; j < 8; ++j) u.s[j] = T[ch*8+j][c];
        *(uint4*)(out + (size_t)(c0 + c) * 768 + k0 + ch * 8) = u.v;
    }
}

// ------ mask encoding probe over first 1024 words (safe in all encodings) ------
// mode: 0=int32(0/1 words)  1=packed bytes  2=float32  3=bf16
__global__ void detectMask(const unsigned* __restrict__ m, int* __restrict__ flag) {
    __shared__ int sB, sH, sF;
    if (threadIdx.x == 0) { sB = 0; sH = 0; sF = 0; }
    __syncthreads();
    int lb = 0, lh = 0, lf = 0;
#pragma unroll
    for (int i = 0; i < 4; ++i) {
        unsigned v = m[threadIdx.x + i * 256];
        if (v == 0x3f800000u) { lf = 1; }
        else if (v > 1u) {
            unsigned b0 = v & 0xffu, b1 = (v >> 8) & 0xffu, b2 = (v >> 16) & 0xffu, b3 = v >> 24;
            bool bytesOK = (b0 <= 1u) && (b1 <= 1u) && (b2 <= 1u) && (b3 <= 1u);
            unsigned h0 = v & 0xffffu, h1 = v >> 16;
            bool halfOK = (h0 == 0u || h0 == 0x3f80u) && (h1 == 0u || h1 == 0x3f80u);
            if (bytesOK) lb = 1; else if (halfOK) lh = 1;
        }
    }
    if (lb) atomicOr(&sB, 1);
    if (lh) atomicOr(&sH, 1);
    if (lf) atomicOr(&sF, 1);
    __syncthreads();
    if (threadIdx.x == 0) *flag = sH ? 3 : (sB ? 1 : (sF ? 2 : 0));
}

// ------ GEMM C = A[M,768] * Bt[N,768]^T + bias.
// MODE0: QKV epilogue, scatter Q,K as [bh][n][d], V transposed as [bh][d][n].
// MODE1: f32 out [M][768].
template<int MODE>
__global__ __launch_bounds__(256)
void gemmBT(const u16* __restrict__ A, const u16* __restrict__ Bt,
            const float* __restrict__ bias,
            u16* __restrict__ qO, u16* __restrict__ kO, u16* __restrict__ vO,
            float* __restrict__ fO) {
    __shared__ __align__(16) u16 As[128][40];   // +8 pad: 2-way frag-read conflicts (free)
    __shared__ __align__(16) u16 Bs[128][40];
    const int K = 768;
    const int tid = threadIdx.x;
    const int lane = tid & 63, w = tid >> 6;
    const int wm = w >> 1, wn = w & 1;
    const int l15 = lane & 15, q = lane >> 4;
    const int m0 = blockIdx.y * 128, n0 = blockIdx.x * 128;
    const int rowS = tid >> 1, cS = (tid & 1) * 2;
    const u16* Ag = A + (size_t)(m0 + rowS) * K;
    const u16* Bg = Bt + (size_t)(n0 + rowS) * K;
    uint4 pa0, pa1, pb0, pb1;
    { const uint4* sa = (const uint4*)Ag; pa0 = sa[cS]; pa1 = sa[cS+1];
      const uint4* sb = (const uint4*)Bg; pb0 = sb[cS]; pb1 = sb[cS+1]; }
    f32x4 acc[4][4];
#pragma unroll
    for (int i=0;i<4;++i)
#pragma unroll
        for (int j=0;j<4;++j) acc[i][j] = zero4();

    for (int kt = 0; kt < 24; ++kt) {
        __syncthreads();
        *(uint4*)&As[rowS][cS*8]   = pa0; *(uint4*)&As[rowS][cS*8+8] = pa1;
        *(uint4*)&Bs[rowS][cS*8]   = pb0; *(uint4*)&Bs[rowS][cS*8+8] = pb1;
        __syncthreads();
        if (kt < 23) {   // register prefetch of next K-slab overlaps MFMA
            const uint4* sa = (const uint4*)(Ag + (kt+1)*32);
            pa0 = sa[cS]; pa1 = sa[cS+1];
            const uint4* sb = (const uint4*)(Bg + (kt+1)*32);
            pb0 = sb[cS]; pb1 = sb[cS+1];
        }
        bf16x8 af[4], bfr[4];
#pragma unroll
        for (int mt=0; mt<4; ++mt) af[mt]  = *(const bf16x8*)&As[wm*64+mt*16+l15][q*8];
#pragma unroll
        for (int nt=0; nt<4; ++nt) bfr[nt] = *(const bf16x8*)&Bs[wn*64+nt*16+l15][q*8];
#pragma unroll
        for (int mt=0; mt<4; ++mt)
#pragma unroll
            for (int nt=0; nt<4; ++nt)
                acc[mt][nt] = MFMA_BF16(af[mt], bfr[nt], acc[mt][nt]);
    }

#pragma unroll
    for (int mt=0; mt<4; ++mt) {
#pragma unroll
        for (int nt=0; nt<4; ++nt) {
            int n = n0 + wn*64 + nt*16 + l15;
            float bv = bias[n];
#pragma unroll
            for (int r=0; r<4; ++r) {
                int m = m0 + wm*64 + mt*16 + q*4 + r;
                float v = acc[mt][nt][r] + bv;
                if (MODE == 0) {
                    int which = n / 768;
                    int rem = n - which*768;
                    int hh = rem >> 6, hd = rem & 63;
                    int b = m >> 11, tok = m & 2047;
                    int bh = b*12 + hh;
                    if (which == 0)      qO[(((size_t)bh)*2048 + tok)*64 + hd] = f2b(v * 0.125f); // fold scale (pow2: exact)
                    else if (which == 1) kO[(((size_t)bh)*2048 + tok)*64 + hd] = f2b(v);
                    else                 vO[(((size_t)bh)*64 + hd)*2048 + tok] = f2b(v);  // direct transposed V
                } else {
                    fO[(size_t)m*768 + n] = v;
                }
            }
        }
    }
}

// ------ fused flash attention: one block = (b, h, 64-row Q tile) ------
__global__ __launch_bounds__(256)
void flashAttn(const u16* __restrict__ Qb, const u16* __restrict__ Kb,
               const u16* __restrict__ Vt, const int* __restrict__ dist,
               const int* __restrict__ mask32, const float* __restrict__ btg,
               const int* __restrict__ maskFlag, u16* __restrict__ attnout) {
    __shared__ __align__(16) u16 Qs[64][72], Ks[64][72], Vs[64][72], Ps[64][72];
    __shared__ float bt[384];
    __shared__ int mrow[64];
    const int tid = threadIdx.x;
    const int lane = tid & 63, w = tid >> 6;
    const int l15 = lane & 15, q = lane >> 4;
    const int b = blockIdx.z, h = blockIdx.y, i0 = blockIdx.x * 64;
    const int bh = b * 12 + h;
    for (int t = tid; t < 384; t += 256) bt[t] = btg[t];   // FIX: was `if (tid<384)` — never loaded bt[256..383]
    const int srow = tid >> 2, sc = (tid & 3) * 2;
    { const uint4* s = (const uint4*)(Qb + ((size_t)bh*2048 + i0 + srow)*64);
      *(uint4*)&Qs[srow][sc*8] = s[sc]; *(uint4*)&Qs[srow][sc*8+8] = s[sc+1]; }
    __syncthreads();
    bf16x8 qf0 = *(const bf16x8*)&Qs[w*16+l15][q*8];       // Q frags constant over j-tiles
    bf16x8 qf1 = *(const bf16x8*)&Qs[w*16+l15][32+q*8];
    f32x4 o[4];
#pragma unroll
    for (int i=0;i<4;++i) o[i] = zero4();
    float mI[4], lI[4];
    const float NEG_INF = -__builtin_inff();
#pragma unroll
    for (int r=0;r<4;++r){ mI[r] = NEG_INF; lI[r] = 0.f; }
    const u16* Kp = Kb + (size_t)bh*2048*64;
    const u16* Vp = Vt + (size_t)bh*64*2048;
    const int mode = *maskFlag;
    const unsigned char* mask8 = (const unsigned char*)mask32;
    const float* maskf = (const float*)mask32;
    const u16* maskh = (const u16*)mask32;
    const int irow = i0 + w*16 + q*4;
    const float LOG2E = 1.4426950408889634f;

    for (int jt = 0; jt < 32; ++jt) {
        const int j0 = jt * 64;
        __syncthreads();
        { const uint4* s = (const uint4*)(Kp + (size_t)(j0+srow)*64);
          *(uint4*)&Ks[srow][sc*8] = s[sc]; *(uint4*)&Ks[srow][sc*8+8] = s[sc+1]; }
        { const uint4* s = (const uint4*)(Vp + (size_t)srow*2048 + j0);
          *(uint4*)&Vs[srow][sc*8] = s[sc]; *(uint4*)&Vs[srow][sc*8+8] = s[sc+1]; }
        if (tid < 64) {
            int j = b*2048 + j0 + tid;
            int mv;
            if (mode == 0)      mv = (mask32[j] != 0);
            else if (mode == 1) mv = (mask8[j] != 0);
            else if (mode == 2) mv = (maskf[j] != 0.0f);
            else                mv = (maskh[j] != 0);
            mrow[tid] = mv;
        }
        __syncthreads();

        f32x4 sA[4];
#pragma unroll
        for (int i=0;i<4;++i) sA[i] = zero4();
#pragma unroll
        for (int ks=0; ks<2; ++ks) {
            bf16x8 a = ks ? qf1 : qf0;
#pragma unroll
            for (int nt=0; nt<4; ++nt) {
                bf16x8 kf = *(const bf16x8*)&Ks[nt*16+l15][ks*32+q*8];
                sA[nt] = MFMA_BF16(a, kf, sA[nt]);
            }
        }

        const int* dp = dist + (size_t)(b*2048 + irow)*2048 + j0;
#pragma unroll
        for (int r=0; r<4; ++r) {
            float sv[4];
#pragma unroll
            for (int nt=0; nt<4; ++nt) {
                int dd = dp[(size_t)r*2048 + nt*16 + l15];
                dd = dd < 0 ? 0 : (dd > 31 ? 31 : dd);
                float bias = bt[dd*12 + h];
                sv[nt] = mrow[nt*16+l15] ? NEG_INF : (sA[nt][r] + bias) * LOG2E;
            }
            float rm = fmaxf(fmaxf(sv[0],sv[1]), fmaxf(sv[2],sv[3]));
#pragma unroll
            for (int off=1; off<16; off<<=1) rm = fmaxf(rm, __shfl_xor(rm, off, 64));
            float mn = fmaxf(mI[r], rm);
            float al = exp2f(mI[r] - mn);
            float ps = 0.f, pj[4];
#pragma unroll
            for (int nt=0; nt<4; ++nt) { pj[nt] = exp2f(sv[nt] - mn); ps += pj[nt]; }
#pragma unroll
            for (int nt=0; nt<4; ++nt) Ps[w*16 + q*4 + r][nt*16 + l15] = f2b(pj[nt]);
#pragma unroll
            for (int off=1; off<16; off<<=1) ps += __shfl_xor(ps, off, 64);
            lI[r] = lI[r]*al + ps;
            mI[r] = mn;
#pragma unroll
            for (int nt=0; nt<4; ++nt) o[nt][r] *= al;
        }
        __syncthreads();
#pragma unroll
        for (int ks=0; ks<2; ++ks) {
            bf16x8 pf = *(const bf16x8*)&Ps[w*16+l15][ks*32+q*8];
#pragma unroll
            for (int nt=0; nt<4; ++nt) {
                bf16x8 vf = *(const bf16x8*)&Vs[nt*16+l15][ks*32+q*8];
                o[nt] = MFMA_BF16(pf, vf, o[nt]);
            }
        }
    }
#pragma unroll
    for (int r=0; r<4; ++r) {
        float inv = 1.0f / lI[r];
        size_t base = ((size_t)b*2048 + i0 + w*16 + q*4 + r)*768 + (size_t)h*64;
#pragma unroll
        for (int nt=0; nt<4; ++nt)
            attnout[base + nt*16 + l15] = f2b(o[nt][r] * inv);
    }
}

extern "C" void kernel_launch(void* const* d_in, const int* in_sizes, int n_in,
                              void* d_out, int out_size, void* d_ws, size_t ws_size,
                              hipStream_t stream) {
    (void)in_sizes; (void)n_in; (void)out_size; (void)ws_size;
    const float* x      = (const float*)d_in[0];
    const int*   dist   = (const int*)d_in[1];
    const int*   mask   = (const int*)d_in[2];
    const float* qkv_w  = (const float*)d_in[3];
    const float* qkv_b  = (const float*)d_in[4];
    const float* out_w  = (const float*)d_in[5];
    const float* out_b  = (const float*)d_in[6];
    const float* btab   = (const float*)d_in[7];
    float* out = (float*)d_out;

    char* ws = (char*)d_ws;
    size_t off = 0;
    auto alloc = [&](size_t bytes) { void* p = ws + off; off += (bytes + 255) & ~(size_t)255; return p; };
    u16* xb      = (u16*)alloc((size_t)4096*768*2);
    u16* wqkvT   = (u16*)alloc((size_t)2304*768*2);
    u16* woutT   = (u16*)alloc((size_t)768*768*2);
    u16* Qb      = (u16*)alloc((size_t)24*2048*64*2);
    u16* Kb      = (u16*)alloc((size_t)24*2048*64*2);
    u16* Vtp     = (u16*)alloc((size_t)24*2048*64*2);
    u16* attnout = (u16*)alloc((size_t)4096*768*2);
    int* flagp   = (int*)alloc(256);

    convX<<<1536, 256, 0, stream>>>(x, xb);
    convTW<<<dim3(36,12), 256, 0, stream>>>(qkv_w, wqkvT, 2304);
    convTW<<<dim3(12,12), 256, 0, stream>>>(out_w, woutT, 768);
    detectMask<<<1, 256, 0, stream>>>((const unsigned*)mask, flagp);
    gemmBT<0><<<dim3(18,32), 256, 0, stream>>>(xb, wqkvT, qkv_b, Qb, Kb, Vtp, nullptr);
    flashAttn<<<dim3(32,12,2), 256, 0, stream>>>(Qb, Kb, Vtp, dist, mask, btab, flagp, attnout);
    gemmBT<1><<<dim3(6,32), 256, 0, stream>>>(attnout, woutT, out_b, nullptr, nullptr, nullptr, out);
}

// Round 4
// 371.882 us; speedup vs baseline: 1.0585x; 1.0585x over previous
//
#include <hip/hip_runtime.h>
#include <hip/hip_bf16.h>

typedef unsigned short u16;
typedef __attribute__((ext_vector_type(8))) short bf16x8;
typedef __attribute__((ext_vector_type(4))) float f32x4;

#define MFMA_BF16(a,b,c) __builtin_amdgcn_mfma_f32_16x16x32_bf16((a),(b),(c),0,0,0)
#define LOG2E 1.4426950408889634f

__device__ __forceinline__ u16 f2b(float f) {
    __hip_bfloat16 h = __float2bfloat16(f);
    u16 u; __builtin_memcpy(&u, &h, 2); return u;
}
__device__ __forceinline__ f32x4 zero4() { f32x4 z = {0.f,0.f,0.f,0.f}; return z; }

// ---------------- convert x (f32) -> bf16, 8 elems/thread ----------------
__global__ __launch_bounds__(256) void convX(const float* __restrict__ in, u16* __restrict__ out) {
    size_t i = ((size_t)blockIdx.x * 256 + threadIdx.x) * 8;
    float4 a = *(const float4*)(in + i);
    float4 b = *(const float4*)(in + i + 4);
    union { u16 s[8]; uint4 v; } u;
    u.s[0]=f2b(a.x); u.s[1]=f2b(a.y); u.s[2]=f2b(a.z); u.s[3]=f2b(a.w);
    u.s[4]=f2b(b.x); u.s[5]=f2b(b.y); u.s[6]=f2b(b.z); u.s[7]=f2b(b.w);
    *(uint4*)(out + i) = u.v;
}

// ------ weight transpose+convert: in [768][C] f32 -> out [C][768] bf16 ------
__global__ __launch_bounds__(256) void convTW(const float* __restrict__ in, u16* __restrict__ out, int C) {
    __shared__ __align__(16) u16 T[64][68];
    int c0 = blockIdx.x * 64, k0 = blockIdx.y * 64;
    int tid = threadIdx.x;
#pragma unroll
    for (int i = 0; i < 4; ++i) {
        int id = tid + i * 256;
        int row = id >> 4, ch = id & 15;
        float4 v = *(const float4*)(in + (size_t)(k0 + row) * C + c0 + ch * 4);
        T[row][ch*4+0] = f2b(v.x); T[row][ch*4+1] = f2b(v.y);
        T[row][ch*4+2] = f2b(v.z); T[row][ch*4+3] = f2b(v.w);
    }
    __syncthreads();
#pragma unroll
    for (int i = 0; i < 2; ++i) {
        int id = tid + i * 256;
        int c = id >> 3, ch = id & 7;
        union { u16 s[8]; uint4 v; } u;
#pragma unroll
        for (int j = 0; j < 8; ++j) u.s[j] = T[ch*8+j][c];
        *(uint4*)(out + (size_t)(c0 + c) * 768 + k0 + ch * 8) = u.v;
    }
}

// ------ V transpose: Vb [bh][2048][64] -> Vt [bh][64][2048] (bf16) ------
__global__ __launch_bounds__(256) void transV(const u16* __restrict__ Vb, u16* __restrict__ Vt) {
    __shared__ __align__(16) u16 T[64][72];
    int blk = blockIdx.x;
    int n0 = (blk & 31) * 64, bh = blk >> 5;
    int tid = threadIdx.x;
    int row = tid >> 2, sc = (tid & 3) * 2;
    const uint4* s = (const uint4*)(Vb + ((size_t)bh * 2048 + n0 + row) * 64);
    *(uint4*)&T[row][sc*8]   = s[sc];
    *(uint4*)&T[row][sc*8+8] = s[sc+1];
    __syncthreads();
#pragma unroll
    for (int i = 0; i < 2; ++i) {
        int id = tid + i * 256;
        int hd = id >> 3, ch = id & 7;
        union { u16 s2[8]; uint4 v; } u;
#pragma unroll
        for (int j = 0; j < 8; ++j) u.s2[j] = T[ch*8+j][hd];
        *(uint4*)(Vt + ((size_t)bh * 64 + hd) * 2048 + n0 + ch * 8) = u.v;
    }
}

// ------ mask: detect encoding (int32/byte/f32/bf16), pack to 64 u64 bitmasks ------
__global__ void detectMaskBits(const unsigned* __restrict__ m, unsigned long long* __restrict__ mbits) {
    __shared__ int sB, sH, sF;
    if (threadIdx.x == 0) { sB = 0; sH = 0; sF = 0; }
    __syncthreads();
    int lb = 0, lh = 0, lf = 0;
#pragma unroll
    for (int i = 0; i < 4; ++i) {
        unsigned v = m[threadIdx.x + i * 256];   // first 4KB: safe under all encodings
        if (v == 0x3f800000u) { lf = 1; }
        else if (v > 1u) {
            unsigned b0 = v & 0xffu, b1 = (v >> 8) & 0xffu, b2 = (v >> 16) & 0xffu, b3 = v >> 24;
            bool bytesOK = (b0 <= 1u) && (b1 <= 1u) && (b2 <= 1u) && (b3 <= 1u);
            unsigned h0 = v & 0xffffu, h1 = v >> 16;
            bool halfOK = (h0 == 0u || h0 == 0x3f80u) && (h1 == 0u || h1 == 0x3f80u);
            if (bytesOK) lb = 1; else if (halfOK) lh = 1;
        }
    }
    if (lb) atomicOr(&sB, 1);
    if (lh) atomicOr(&sH, 1);
    if (lf) atomicOr(&sF, 1);
    __syncthreads();
    int mode = sH ? 3 : (sB ? 1 : (sF ? 2 : 0));
    const unsigned char* m8 = (const unsigned char*)m;
    const u16* mh = (const u16*)m;
    const float* mf = (const float*)m;
    const int* mi = (const int*)m;
    for (int it = 0; it < 16; ++it) {
        int e = it * 256 + threadIdx.x;          // e in [0,4096) = b*2048 + j
        int pred;
        if (mode == 0)      pred = (mi[e] != 0);
        else if (mode == 1) pred = (m8[e] != 0);
        else if (mode == 2) pred = (mf[e] != 0.0f);
        else                pred = (mh[e] != 0);
        unsigned long long bal = __ballot(pred);
        if ((threadIdx.x & 63) == 0) mbits[it * 4 + (threadIdx.x >> 6)] = bal;
    }
}

// ------ GEMM C = A[M,768] * Bt[N,768]^T + bias.
// MODE0: QKV epilogue -> Q,K,V all [bh][tok][hd] bf16 (Q pre-scaled by 0.125*log2e).
// MODE1: f32 out [M][768].
template<int MODE>
__global__ __launch_bounds__(256)
void gemmBT(const u16* __restrict__ A, const u16* __restrict__ Bt,
            const float* __restrict__ bias,
            u16* __restrict__ qO, u16* __restrict__ kO, u16* __restrict__ vO,
            float* __restrict__ fO) {
    __shared__ __align__(16) u16 As[128][40];
    __shared__ __align__(16) u16 Bs[128][40];
    const int K = 768;
    const int tid = threadIdx.x;
    const int lane = tid & 63, w = tid >> 6;
    const int wm = w >> 1, wn = w & 1;
    const int l15 = lane & 15, q = lane >> 4;
    const int m0 = blockIdx.y * 128, n0 = blockIdx.x * 128;
    const int rowS = tid >> 1, cS = (tid & 1) * 2;
    const u16* Ag = A + (size_t)(m0 + rowS) * K;
    const u16* Bg = Bt + (size_t)(n0 + rowS) * K;
    uint4 pa0, pa1, pb0, pb1;
    { const uint4* sa = (const uint4*)Ag; pa0 = sa[cS]; pa1 = sa[cS+1];
      const uint4* sb = (const uint4*)Bg; pb0 = sb[cS]; pb1 = sb[cS+1]; }
    f32x4 acc[4][4];
#pragma unroll
    for (int i=0;i<4;++i)
#pragma unroll
        for (int j=0;j<4;++j) acc[i][j] = zero4();

    for (int kt = 0; kt < 24; ++kt) {
        __syncthreads();
        *(uint4*)&As[rowS][cS*8]   = pa0; *(uint4*)&As[rowS][cS*8+8] = pa1;
        *(uint4*)&Bs[rowS][cS*8]   = pb0; *(uint4*)&Bs[rowS][cS*8+8] = pb1;
        __syncthreads();
        if (kt < 23) {
            const uint4* sa = (const uint4*)(Ag + (kt+1)*32);
            pa0 = sa[cS]; pa1 = sa[cS+1];
            const uint4* sb = (const uint4*)(Bg + (kt+1)*32);
            pb0 = sb[cS]; pb1 = sb[cS+1];
        }
        bf16x8 af[4], bfr[4];
#pragma unroll
        for (int mt=0; mt<4; ++mt) af[mt]  = *(const bf16x8*)&As[wm*64+mt*16+l15][q*8];
#pragma unroll
        for (int nt=0; nt<4; ++nt) bfr[nt] = *(const bf16x8*)&Bs[wn*64+nt*16+l15][q*8];
#pragma unroll
        for (int mt=0; mt<4; ++mt)
#pragma unroll
            for (int nt=0; nt<4; ++nt)
                acc[mt][nt] = MFMA_BF16(af[mt], bfr[nt], acc[mt][nt]);
    }

#pragma unroll
    for (int mt=0; mt<4; ++mt) {
#pragma unroll
        for (int nt=0; nt<4; ++nt) {
            int n = n0 + wn*64 + nt*16 + l15;
            float bv = bias[n];
#pragma unroll
            for (int r=0; r<4; ++r) {
                int m = m0 + wm*64 + mt*16 + q*4 + r;
                float v = acc[mt][nt][r] + bv;
                if (MODE == 0) {
                    int which = n / 768;
                    int rem = n - which*768;
                    int hh = rem >> 6, hd = rem & 63;
                    int b = m >> 11, tok = m & 2047;
                    size_t di = (((size_t)(b*12 + hh))*2048 + tok)*64 + hd;
                    if (which == 0)      qO[di] = f2b(v * (0.125f * LOG2E));  // fold scale+log2e into Q
                    else if (which == 1) kO[di] = f2b(v);
                    else                 vO[di] = f2b(v);
                } else {
                    fO[(size_t)m*768 + n] = v;
                }
            }
        }
    }
}

// ------ fused flash attention, S^T formulation: one block = (b, h, 64-row Q tile) ------
// S^T = K·Q^T via MFMA(A=K, B=Q): softmax dim j lands in registers (16/lane),
// per-lane column i = l15. O^T = V^T·P^T via MFMA(A=Vt, B=P-exchanged).
// No LDS staging, no in-loop barriers; K/V frags direct from global (L2-resident).
__global__ __launch_bounds__(256)
void flashAttn(const u16* __restrict__ Qb, const u16* __restrict__ Kb,
               const u16* __restrict__ Vt, const int* __restrict__ dist,
               const unsigned long long* __restrict__ mbits,
               const float* __restrict__ btg, u16* __restrict__ attnout) {
    __shared__ float bt[32];
    __shared__ __align__(16) u16 Os[4][16][72];
    const int tid = threadIdx.x;
    const int lane = tid & 63, w = tid >> 6;
    const int l15 = lane & 15, q = lane >> 4;
    const int b = blockIdx.z, h = blockIdx.y, i0 = blockIdx.x * 64;
    const int bh = b * 12 + h;
    const float NEG_INF = -__builtin_inff();
    if (tid < 32) bt[tid] = btg[tid*12 + h] * LOG2E;   // log2-domain bias, head-sliced
    __syncthreads();

    const int iRow = i0 + w*16 + l15;                  // this lane's i (output column)
    const u16* Qp = Qb + ((size_t)bh*2048 + iRow)*64;
    bf16x8 qB0 = *(const bf16x8*)(Qp + q*8);           // B-frag: Q[i=l15][d=q*8.. ], ks=0
    bf16x8 qB1 = *(const bf16x8*)(Qp + 32 + q*8);      // ks=1
    const u16* Kp  = Kb + (size_t)bh*2048*64 + l15*64 + q*8;        // K[j=mt*16+l15][d=ks*32+q*8]
    const u16* Vr0 = Vt + ((size_t)bh*64 + l15)*2048 + q*8;         // Vt[d=mt*16+l15][j]
    const u16* Vr1 = Vr0 + 16*2048;
    const u16* Vr2 = Vr0 + 32*2048;
    const u16* Vr3 = Vr0 + 48*2048;
    const int* dp = dist + ((size_t)(b*2048 + iRow))*2048 + q*4;    // +j0+mt*16, 4 consecutive r
    const unsigned long long* mbp = mbits + b*32;
    const int srcL0 = ((2*q)   & 3)*16 + l15;          // P-exchange source lanes
    const int srcL1 = ((2*q+1) & 3)*16 + l15;

    f32x4 o0 = zero4(), o1 = zero4(), o2 = zero4(), o3 = zero4();
    float mI = NEG_INF, lI = 0.f;

    for (int jt = 0; jt < 32; ++jt) {
        const int j0 = jt * 64;
        // --- issue loads (no barriers; waves independent) ---
        const u16* kb = Kp + (size_t)j0*64;
        bf16x8 kA[4][2];
#pragma unroll
        for (int mt = 0; mt < 4; ++mt) {
            kA[mt][0] = *(const bf16x8*)(kb + mt*1024);
            kA[mt][1] = *(const bf16x8*)(kb + mt*1024 + 32);
        }
        int4 dv[4];
#pragma unroll
        for (int mt = 0; mt < 4; ++mt) dv[mt] = *(const int4*)(dp + j0 + mt*16);
        unsigned long long mb = mbp[jt];

        // --- S^T = K·Q^T ---
        f32x4 s0 = zero4(), s1 = zero4(), s2 = zero4(), s3 = zero4();
        s0 = MFMA_BF16(kA[0][0], qB0, s0); s0 = MFMA_BF16(kA[0][1], qB1, s0);
        s1 = MFMA_BF16(kA[1][0], qB0, s1); s1 = MFMA_BF16(kA[1][1], qB1, s1);
        s2 = MFMA_BF16(kA[2][0], qB0, s2); s2 = MFMA_BF16(kA[2][1], qB1, s2);
        s3 = MFMA_BF16(kA[3][0], qB0, s3); s3 = MFMA_BF16(kA[3][1], qB1, s3);

        // V frags (issue now; softmax VALU covers the latency)
        bf16x8 vA[4][2];
        vA[0][0] = *(const bf16x8*)(Vr0 + j0); vA[0][1] = *(const bf16x8*)(Vr0 + j0 + 32);
        vA[1][0] = *(const bf16x8*)(Vr1 + j0); vA[1][1] = *(const bf16x8*)(Vr1 + j0 + 32);
        vA[2][0] = *(const bf16x8*)(Vr2 + j0); vA[2][1] = *(const bf16x8*)(Vr2 + j0 + 32);
        vA[3][0] = *(const bf16x8*)(Vr3 + j0); vA[3][1] = *(const bf16x8*)(Vr3 + j0 + 32);

        // --- bias + mask (log2 domain); jl = mt*16 + q*4 + r, bit jl of mb ---
        unsigned long long ms = mb >> (q*4);
        unsigned mlo = (unsigned)ms, mhi = (unsigned)(ms >> 32);
        float sv[4][4];
#pragma unroll
        for (int mt = 0; mt < 4; ++mt) {
            const f32x4 sm = mt==0 ? s0 : (mt==1 ? s1 : (mt==2 ? s2 : s3));
            const int4 d4 = dv[mt];
#pragma unroll
            for (int r = 0; r < 4; ++r) {
                int dd = (r==0 ? d4.x : r==1 ? d4.y : r==2 ? d4.z : d4.w) & 31;
                float x = sm[r] + bt[dd];
                unsigned bit = (mt < 2) ? ((mlo >> (mt*16 + r)) & 1u)
                                        : ((mhi >> ((mt-2)*16 + r)) & 1u);
                sv[mt][r] = bit ? NEG_INF : x;
            }
        }

        // --- online softmax per column i (in-lane over 16 j + 2 cross-quad shfl) ---
        float rm = sv[0][0];
#pragma unroll
        for (int mt = 0; mt < 4; ++mt)
#pragma unroll
            for (int r = 0; r < 4; ++r) rm = fmaxf(rm, sv[mt][r]);
        rm = fmaxf(rm, __shfl_xor(rm, 16, 64));
        rm = fmaxf(rm, __shfl_xor(rm, 32, 64));
        float mn = fmaxf(mI, rm);
        float al = exp2f(mI - mn);
        float p[4][4]; float ps = 0.f;
#pragma unroll
        for (int mt = 0; mt < 4; ++mt)
#pragma unroll
            for (int r = 0; r < 4; ++r) { p[mt][r] = exp2f(sv[mt][r] - mn); ps += p[mt][r]; }
        ps += __shfl_xor(ps, 16, 64);
        ps += __shfl_xor(ps, 32, 64);
        lI = lI * al + ps;
        mI = mn;
#pragma unroll
        for (int r = 0; r < 4; ++r) { o0[r] *= al; o1[r] *= al; o2[r] *= al; o3[r] *= al; }

        // --- pack P to bf16 pairs ---
        unsigned pk[4][2];
#pragma unroll
        for (int mt = 0; mt < 4; ++mt) {
            pk[mt][0] = (unsigned)f2b(p[mt][0]) | ((unsigned)f2b(p[mt][1]) << 16);
            pk[mt][1] = (unsigned)f2b(p[mt][2]) | ((unsigned)f2b(p[mt][3]) << 16);
        }
        // --- exchange C-layout -> B-frag layout (16 bpermute + 8 select), then PV ---
#pragma unroll
        for (int ks = 0; ks < 2; ++ks) {
            union { unsigned d[4]; bf16x8 v; } pb;
#pragma unroll
            for (int s = 0; s < 4; ++s) {
                int sl = (s >> 1) ? srcL1 : srcL0;
                int u0 = __shfl((int)pk[2*ks    ][s & 1], sl, 64);
                int u1 = __shfl((int)pk[2*ks + 1][s & 1], sl, 64);
                pb.d[s] = (q >> 1) ? (unsigned)u1 : (unsigned)u0;
            }
            o0 = MFMA_BF16(vA[0][ks], pb.v, o0);
            o1 = MFMA_BF16(vA[1][ks], pb.v, o1);
            o2 = MFMA_BF16(vA[2][ks], pb.v, o2);
            o3 = MFMA_BF16(vA[3][ks], pb.v, o3);
        }
    }

    // --- epilogue: normalize, LDS bounce O^T -> row-major, coalesced store ---
    float inv = 1.0f / lI;
#pragma unroll
    for (int r = 0; r < 4; ++r) {
        Os[w][l15][ 0 + q*4 + r] = f2b(o0[r] * inv);
        Os[w][l15][16 + q*4 + r] = f2b(o1[r] * inv);
        Os[w][l15][32 + q*4 + r] = f2b(o2[r] * inv);
        Os[w][l15][48 + q*4 + r] = f2b(o3[r] * inv);
    }
    __syncthreads();
    int rr = lane >> 2, cc = lane & 3;
    uint4 a0 = *(const uint4*)&Os[w][rr][cc*16];
    uint4 a1 = *(const uint4*)&Os[w][rr][cc*16 + 8];
    size_t orow = ((size_t)b*2048 + i0 + w*16 + rr)*768 + h*64 + cc*16;
    *(uint4*)(attnout + orow)     = a0;
    *(uint4*)(attnout + orow + 8) = a1;
}

extern "C" void kernel_launch(void* const* d_in, const int* in_sizes, int n_in,
                              void* d_out, int out_size, void* d_ws, size_t ws_size,
                              hipStream_t stream) {
    (void)in_sizes; (void)n_in; (void)out_size; (void)ws_size;
    const float* x      = (const float*)d_in[0];
    const int*   dist   = (const int*)d_in[1];
    const int*   mask   = (const int*)d_in[2];
    const float* qkv_w  = (const float*)d_in[3];
    const float* qkv_b  = (const float*)d_in[4];
    const float* out_w  = (const float*)d_in[5];
    const float* out_b  = (const float*)d_in[6];
    const float* btab   = (const float*)d_in[7];
    float* out = (float*)d_out;

    char* ws = (char*)d_ws;
    size_t off = 0;
    auto alloc = [&](size_t bytes) { void* p = ws + off; off += (bytes + 255) & ~(size_t)255; return p; };
    u16* xb      = (u16*)alloc((size_t)4096*768*2);
    u16* wqkvT   = (u16*)alloc((size_t)2304*768*2);
    u16* woutT   = (u16*)alloc((size_t)768*768*2);
    u16* Qb      = (u16*)alloc((size_t)24*2048*64*2);
    u16* Kb      = (u16*)alloc((size_t)24*2048*64*2);
    u16* Vb      = (u16*)alloc((size_t)24*2048*64*2);
    u16* Vtp     = (u16*)alloc((size_t)24*2048*64*2);
    u16* attnout = (u16*)alloc((size_t)4096*768*2);
    unsigned long long* mbits = (unsigned long long*)alloc(64*8);

    convX<<<1536, 256, 0, stream>>>(x, xb);
    convTW<<<dim3(36,12), 256, 0, stream>>>(qkv_w, wqkvT, 2304);
    convTW<<<dim3(12,12), 256, 0, stream>>>(out_w, woutT, 768);
    detectMaskBits<<<1, 256, 0, stream>>>((const unsigned*)mask, mbits);
    gemmBT<0><<<dim3(18,32), 256, 0, stream>>>(xb, wqkvT, qkv_b, Qb, Kb, Vb, nullptr);
    transV<<<768, 256, 0, stream>>>(Vb, Vtp);
    flashAttn<<<dim3(32,12,2), 256, 0, stream>>>(Qb, Kb, Vtp, dist, mbits, btab, attnout);
    gemmBT<1><<<dim3(6,32), 256, 0, stream>>>(attnout, woutT, out_b, nullptr, nullptr, nullptr, out);
}